// Round 13
// baseline (270.620 us; speedup 1.0000x reference)
//
#include <hip/hip_runtime.h>
#include <hip/hip_bf16.h>

// LFQ argmax, round 13: r12 (tt=4, LDS-shared B) with 32-code tiles.
// r12 post-mortem: LDS dbuf 64 KB -> only 1 block/CU resident (Occupancy
// 22.6 -> 11.4% vs r11), 1 wave/SIMD, no TLP -> MfmaUtil fell to 45% and
// stage1 regressed 184->202 us despite halved LDS reads. Fix: tile = 32 codes
// (hi+lo 16 KB), double-buffer 32 KB -> 2 independent blocks/CU co-resident
// (8 waves/CU TLP; barriers of one block overlap MFMA of the other).
// Numerics (validated r6-r12): 3-term split-bf16, 7-bit j-pack top-2
// (pk = 127 - (t*2+s), jj in [0,128)), per-split top-2, exact rescore of
// MARGIN band with band-count shortcut. Output float32[16385].
#define NT 16384
#define ND 128
#define NC 16384
#define NSPLIT 8
#define MARGIN 0.02f      // >20x the (split + 7-bit packing) comparison error
#define TILE_BYTES 16384  // 32 codes x 128 dims x 2B x (hi+lo)
#define NTILES 64         // tiles per 2048-code slice

typedef __bf16 bf16x8 __attribute__((ext_vector_type(8)));
typedef unsigned short u16x8 __attribute__((ext_vector_type(8)));
typedef float f32x4 __attribute__((ext_vector_type(4)));

static __device__ __forceinline__ unsigned short f2bf(float f) {
    unsigned u = __float_as_uint(f);
    return (unsigned short)((u + 0x7FFFu + ((u >> 16) & 1u)) >> 16);
}
static __device__ __forceinline__ float bf2f(unsigned short u) {
    return __uint_as_float(((unsigned)u) << 16);
}
static __device__ __forceinline__ bf16x8 u2b(u16x8 u) {
    return __builtin_bit_cast(bf16x8, u);
}
static __device__ __forceinline__ void gl2lds(const void* g, void* l) {
    __builtin_amdgcn_global_load_lds(
        (const __attribute__((address_space(1))) unsigned int*)g,
        (__attribute__((address_space(3))) unsigned int*)l, 16, 0, 0);
}

// ---- codebook fp32 -> bf16 hi/lo, 32-code tile images w/ chunk rotation ----
// Tile t: u16 span [t*8192, t*8192+8192): hi 4096 | lo 4096.
// Element (code c, dim d): r=c&31, pos=((d>>3)+r)&15 ->
//   hi at t*8192 + r*128 + pos*8 + (d&7); lo at +4096.
__global__ __launch_bounds__(512) void lfq_convert_cb(
    const float4* __restrict__ cb4, unsigned short* __restrict__ cbs)
{
    const unsigned i = blockIdx.x * 512 + threadIdx.x;   // 0..524287
    float4 v = cb4[i];
    const unsigned c    = i >> 5;
    const unsigned d0   = (i & 31u) << 2;
    const unsigned tile = c >> 5, r = c & 31u;
    const unsigned pos  = ((d0 >> 3) + r) & 15u;
    const unsigned base = tile * 8192u + r * 128u + pos * 8u + (d0 & 7u);
    ushort4 h, l;
    h.x = f2bf(v.x); l.x = f2bf(v.x - bf2f(h.x));
    h.y = f2bf(v.y); l.y = f2bf(v.y - bf2f(h.y));
    h.z = f2bf(v.z); l.z = f2bf(v.z - bf2f(h.z));
    h.w = f2bf(v.w); l.w = f2bf(v.w - bf2f(h.w));
    *(ushort4*)(cbs + base)        = h;
    *(ushort4*)(cbs + base + 4096) = l;
}

// round-3/4-validated exact fp32 dot (reads ORIGINAL fp32 codebook)
static __device__ __forceinline__ float exact_dot(
    const float4* __restrict__ xr4, const float* __restrict__ cf, int cidx)
{
    const float4* cr = (const float4*)(cf + (size_t)cidx * ND);
    float a0 = 0.f, a1 = 0.f, a2 = 0.f, a3 = 0.f;
#pragma unroll
    for (int i = 0; i < 32; i += 4) {
        float4 x0 = xr4[i+0], x1 = xr4[i+1], x2 = xr4[i+2], x3 = xr4[i+3];
        float4 c0 = cr[i+0],  c1 = cr[i+1],  c2 = cr[i+2],  c3 = cr[i+3];
        a0 += x0.x*c0.x + x0.y*c0.y + x0.z*c0.z + x0.w*c0.w;
        a1 += x1.x*c1.x + x1.y*c1.y + x1.z*c1.z + x1.w*c1.w;
        a2 += x2.x*c2.x + x2.y*c2.y + x2.z*c2.z + x2.w*c2.w;
        a3 += x3.x*c3.x + x3.y*c3.y + x3.z*c3.z + x3.w*c3.w;
    }
    return (a0 + a1) + (a2 + a3);
}

// ---- stage 1: grid 512 = 64 token-blocks(256 tok) x 8 splits (XCD-affine) ---
// Block: 256 threads = 4 waves; wave w covers tokens t0+w*64..+63 (tt=4),
// all waves sweep the 2048-code slice from LDS (32-code tiles).
__global__ __launch_bounds__(256, 1) void lfq_stage1(
    const float* __restrict__ xf, const unsigned short* __restrict__ cbs,
    float* __restrict__ sb1, float* __restrict__ sb2,
    int* __restrict__ si1, int* __restrict__ si2)
{
    const int split = blockIdx.x & 7;
    const int tb    = blockIdx.x >> 3;
    const int t0    = tb * 256;
    const int tid   = threadIdx.x;
    const int w     = tid >> 6;       // wave id = token-group, 0..3
    const int lane  = tid & 63;
    const int n     = lane & 15;
    const int quad  = lane >> 4;

    __shared__ __attribute__((aligned(16))) unsigned char lds[2 * TILE_BYTES];

    // A fragments: tokens t0 + w*64 + tt*16 + n, tt=0..3; fp32 -> bf16 hi/lo.
    bf16x8 ah[4][4], al[4][4];
#pragma unroll
    for (int tt = 0; tt < 4; ++tt) {
        const float* xr = xf + (size_t)(t0 + w * 64 + tt * 16 + n) * ND + quad * 8;
#pragma unroll
        for (int kk = 0; kk < 4; ++kk) {
            float4 v0 = *(const float4*)(xr + kk * 32);
            float4 v1 = *(const float4*)(xr + kk * 32 + 4);
            u16x8 hu, lu;
            hu[0] = f2bf(v0.x); lu[0] = f2bf(v0.x - bf2f(hu[0]));
            hu[1] = f2bf(v0.y); lu[1] = f2bf(v0.y - bf2f(hu[1]));
            hu[2] = f2bf(v0.z); lu[2] = f2bf(v0.z - bf2f(hu[2]));
            hu[3] = f2bf(v0.w); lu[3] = f2bf(v0.w - bf2f(hu[3]));
            hu[4] = f2bf(v1.x); lu[4] = f2bf(v1.x - bf2f(hu[4]));
            hu[5] = f2bf(v1.y); lu[5] = f2bf(v1.y - bf2f(hu[5]));
            hu[6] = f2bf(v1.z); lu[6] = f2bf(v1.z - bf2f(hu[6]));
            hu[7] = f2bf(v1.w); lu[7] = f2bf(v1.w - bf2f(hu[7]));
            ah[tt][kk] = u2b(hu);
            al[tt][kk] = u2b(lu);
        }
    }

    float b1[4][4], b2[4][4];
#pragma unroll
    for (int tt = 0; tt < 4; ++tt)
#pragma unroll
        for (int r = 0; r < 4; ++r) { b1[tt][r] = -3.0e38f; b2[tt][r] = -3.0e38f; }

    const unsigned char* gtiles =
        (const unsigned char*)cbs + (size_t)(split * NTILES) * TILE_BYTES;
    const unsigned sgo  = (unsigned)(tid * 16);   // global per-lane (contiguous)
    const unsigned ldso = (unsigned)(w * 1024);   // wave-uniform LDS segment

    // stage tile 0 into buffer 0 (4 rounds x 4 KB)
#pragma unroll
    for (int rd = 0; rd < 4; ++rd)
        gl2lds(gtiles + rd * 4096 + sgo, &lds[rd * 4096 + ldso]);
    __syncthreads();

    for (int t = 0; t < NTILES; ++t) {
        const unsigned bufo = (unsigned)(t & 1) * TILE_BYTES;
        if (t < NTILES - 1) {      // async prefetch of next tile (other buffer)
            const unsigned char* g = gtiles + (size_t)(t + 1) * TILE_BYTES;
            const unsigned nbo = (unsigned)((t + 1) & 1) * TILE_BYTES;
#pragma unroll
            for (int rd = 0; rd < 4; ++rd)
                gl2lds(g + rd * 4096 + sgo, &lds[nbo + rd * 4096 + ldso]);
        }
#pragma unroll
        for (int s = 0; s < 2; ++s) {
            const int r = s * 16 + n;                  // code row in tile, 0..31
            const unsigned rowh = bufo + (unsigned)r * 256;
            const unsigned rowl = rowh + 4096 * 2;     // lo half (+8192 B)
            const unsigned p0 = (unsigned)(quad + r) & 15u;
            const unsigned o0 = ((p0      ) & 15u) << 4;
            const unsigned o1 = ((p0 +  4u) & 15u) << 4;
            const unsigned o2 = ((p0 +  8u) & 15u) << 4;
            const unsigned o3 = ((p0 + 12u) & 15u) << 4;

            f32x4 a0 = {0.f,0.f,0.f,0.f}, a1 = {0.f,0.f,0.f,0.f};
            f32x4 a2 = {0.f,0.f,0.f,0.f}, a3 = {0.f,0.f,0.f,0.f};
            {   // hi B fragments: ah*Bh + al*Bh (32 MFMAs)
                bf16x8 q0 = *(const bf16x8*)&lds[rowh + o0];
                bf16x8 q1 = *(const bf16x8*)&lds[rowh + o1];
                bf16x8 q2 = *(const bf16x8*)&lds[rowh + o2];
                bf16x8 q3 = *(const bf16x8*)&lds[rowh + o3];
                a0 = __builtin_amdgcn_mfma_f32_16x16x32_bf16(ah[0][0], q0, a0, 0,0,0);
                a1 = __builtin_amdgcn_mfma_f32_16x16x32_bf16(ah[1][0], q0, a1, 0,0,0);
                a2 = __builtin_amdgcn_mfma_f32_16x16x32_bf16(ah[2][0], q0, a2, 0,0,0);
                a3 = __builtin_amdgcn_mfma_f32_16x16x32_bf16(ah[3][0], q0, a3, 0,0,0);
                a0 = __builtin_amdgcn_mfma_f32_16x16x32_bf16(ah[0][1], q1, a0, 0,0,0);
                a1 = __builtin_amdgcn_mfma_f32_16x16x32_bf16(ah[1][1], q1, a1, 0,0,0);
                a2 = __builtin_amdgcn_mfma_f32_16x16x32_bf16(ah[2][1], q1, a2, 0,0,0);
                a3 = __builtin_amdgcn_mfma_f32_16x16x32_bf16(ah[3][1], q1, a3, 0,0,0);
                a0 = __builtin_amdgcn_mfma_f32_16x16x32_bf16(ah[0][2], q2, a0, 0,0,0);
                a1 = __builtin_amdgcn_mfma_f32_16x16x32_bf16(ah[1][2], q2, a1, 0,0,0);
                a2 = __builtin_amdgcn_mfma_f32_16x16x32_bf16(ah[2][2], q2, a2, 0,0,0);
                a3 = __builtin_amdgcn_mfma_f32_16x16x32_bf16(ah[3][2], q2, a3, 0,0,0);
                a0 = __builtin_amdgcn_mfma_f32_16x16x32_bf16(ah[0][3], q3, a0, 0,0,0);
                a1 = __builtin_amdgcn_mfma_f32_16x16x32_bf16(ah[1][3], q3, a1, 0,0,0);
                a2 = __builtin_amdgcn_mfma_f32_16x16x32_bf16(ah[2][3], q3, a2, 0,0,0);
                a3 = __builtin_amdgcn_mfma_f32_16x16x32_bf16(ah[3][3], q3, a3, 0,0,0);
                a0 = __builtin_amdgcn_mfma_f32_16x16x32_bf16(al[0][0], q0, a0, 0,0,0);
                a1 = __builtin_amdgcn_mfma_f32_16x16x32_bf16(al[1][0], q0, a1, 0,0,0);
                a2 = __builtin_amdgcn_mfma_f32_16x16x32_bf16(al[2][0], q0, a2, 0,0,0);
                a3 = __builtin_amdgcn_mfma_f32_16x16x32_bf16(al[3][0], q0, a3, 0,0,0);
                a0 = __builtin_amdgcn_mfma_f32_16x16x32_bf16(al[0][1], q1, a0, 0,0,0);
                a1 = __builtin_amdgcn_mfma_f32_16x16x32_bf16(al[1][1], q1, a1, 0,0,0);
                a2 = __builtin_amdgcn_mfma_f32_16x16x32_bf16(al[2][1], q1, a2, 0,0,0);
                a3 = __builtin_amdgcn_mfma_f32_16x16x32_bf16(al[3][1], q1, a3, 0,0,0);
                a0 = __builtin_amdgcn_mfma_f32_16x16x32_bf16(al[0][2], q2, a0, 0,0,0);
                a1 = __builtin_amdgcn_mfma_f32_16x16x32_bf16(al[1][2], q2, a1, 0,0,0);
                a2 = __builtin_amdgcn_mfma_f32_16x16x32_bf16(al[2][2], q2, a2, 0,0,0);
                a3 = __builtin_amdgcn_mfma_f32_16x16x32_bf16(al[3][2], q2, a3, 0,0,0);
                a0 = __builtin_amdgcn_mfma_f32_16x16x32_bf16(al[0][3], q3, a0, 0,0,0);
                a1 = __builtin_amdgcn_mfma_f32_16x16x32_bf16(al[1][3], q3, a1, 0,0,0);
                a2 = __builtin_amdgcn_mfma_f32_16x16x32_bf16(al[2][3], q3, a2, 0,0,0);
                a3 = __builtin_amdgcn_mfma_f32_16x16x32_bf16(al[3][3], q3, a3, 0,0,0);
            }
            {   // lo B fragments: ah*Bl (16 MFMAs)
                bf16x8 q0 = *(const bf16x8*)&lds[rowl + o0];
                bf16x8 q1 = *(const bf16x8*)&lds[rowl + o1];
                bf16x8 q2 = *(const bf16x8*)&lds[rowl + o2];
                bf16x8 q3 = *(const bf16x8*)&lds[rowl + o3];
                a0 = __builtin_amdgcn_mfma_f32_16x16x32_bf16(ah[0][0], q0, a0, 0,0,0);
                a1 = __builtin_amdgcn_mfma_f32_16x16x32_bf16(ah[1][0], q0, a1, 0,0,0);
                a2 = __builtin_amdgcn_mfma_f32_16x16x32_bf16(ah[2][0], q0, a2, 0,0,0);
                a3 = __builtin_amdgcn_mfma_f32_16x16x32_bf16(ah[3][0], q0, a3, 0,0,0);
                a0 = __builtin_amdgcn_mfma_f32_16x16x32_bf16(ah[0][1], q1, a0, 0,0,0);
                a1 = __builtin_amdgcn_mfma_f32_16x16x32_bf16(ah[1][1], q1, a1, 0,0,0);
                a2 = __builtin_amdgcn_mfma_f32_16x16x32_bf16(ah[2][1], q1, a2, 0,0,0);
                a3 = __builtin_amdgcn_mfma_f32_16x16x32_bf16(ah[3][1], q1, a3, 0,0,0);
                a0 = __builtin_amdgcn_mfma_f32_16x16x32_bf16(ah[0][2], q2, a0, 0,0,0);
                a1 = __builtin_amdgcn_mfma_f32_16x16x32_bf16(ah[1][2], q2, a1, 0,0,0);
                a2 = __builtin_amdgcn_mfma_f32_16x16x32_bf16(ah[2][2], q2, a2, 0,0,0);
                a3 = __builtin_amdgcn_mfma_f32_16x16x32_bf16(ah[3][2], q2, a3, 0,0,0);
                a0 = __builtin_amdgcn_mfma_f32_16x16x32_bf16(ah[0][3], q3, a0, 0,0,0);
                a1 = __builtin_amdgcn_mfma_f32_16x16x32_bf16(ah[1][3], q3, a1, 0,0,0);
                a2 = __builtin_amdgcn_mfma_f32_16x16x32_bf16(ah[2][3], q3, a2, 0,0,0);
                a3 = __builtin_amdgcn_mfma_f32_16x16x32_bf16(ah[3][3], q3, a3, 0,0,0);
            }
            const unsigned pk = (unsigned)(127 - (t * 2 + s));
#pragma unroll
            for (int r4 = 0; r4 < 4; ++r4) {
                float p0v = __uint_as_float((__float_as_uint(a0[r4]) & 0xFFFFFF80u) | pk);
                b2[0][r4] = __builtin_amdgcn_fmed3f(p0v, b1[0][r4], b2[0][r4]);
                b1[0][r4] = fmaxf(p0v, b1[0][r4]);
                float p1v = __uint_as_float((__float_as_uint(a1[r4]) & 0xFFFFFF80u) | pk);
                b2[1][r4] = __builtin_amdgcn_fmed3f(p1v, b1[1][r4], b2[1][r4]);
                b1[1][r4] = fmaxf(p1v, b1[1][r4]);
                float p2v = __uint_as_float((__float_as_uint(a2[r4]) & 0xFFFFFF80u) | pk);
                b2[2][r4] = __builtin_amdgcn_fmed3f(p2v, b1[2][r4], b2[2][r4]);
                b1[2][r4] = fmaxf(p2v, b1[2][r4]);
                float p3v = __uint_as_float((__float_as_uint(a3[r4]) & 0xFFFFFF80u) | pk);
                b2[3][r4] = __builtin_amdgcn_fmed3f(p3v, b1[3][r4], b2[3][r4]);
                b1[3][r4] = fmaxf(p3v, b1[3][r4]);
            }
        }
        __syncthreads();   // drains prefetch (vmcnt) + protects buffer swap
    }

    // unpack (score, code) and cross-lane top-2 merge over 16 code-lanes
    const int cb_base = split * (NC / NSPLIT);
    float v1[4][4], v2[4][4];
    int   c1[4][4], c2[4][4];
#pragma unroll
    for (int tt = 0; tt < 4; ++tt)
#pragma unroll
        for (int r = 0; r < 4; ++r) {
            int j1 = 127 - (int)(__float_as_uint(b1[tt][r]) & 127u);
            int j2 = 127 - (int)(__float_as_uint(b2[tt][r]) & 127u);
            v1[tt][r] = b1[tt][r]; c1[tt][r] = cb_base + j1 * 16 + n;
            v2[tt][r] = b2[tt][r]; c2[tt][r] = cb_base + j2 * 16 + n;
        }

#pragma unroll
    for (int tt = 0; tt < 4; ++tt)
#pragma unroll
        for (int r = 0; r < 4; ++r) {
#pragma unroll
            for (int off = 1; off < 16; off <<= 1) {
                float ob1 = __shfl_xor(v1[tt][r], off, 64);
                int   oi1 = __shfl_xor(c1[tt][r], off, 64);
                float ob2 = __shfl_xor(v2[tt][r], off, 64);
                int   oi2 = __shfl_xor(c2[tt][r], off, 64);
                bool gt = (ob1 > v1[tt][r]) ||
                          (ob1 == v1[tt][r] && oi1 < c1[tt][r]);
                float ls = gt ? v1[tt][r] : ob1;
                int   li = gt ? c1[tt][r] : oi1;
                float ws_ = gt ? ob2 : v2[tt][r];
                int   wi = gt ? oi2 : c2[tt][r];
                bool s2 = (ls > ws_) || (ls == ws_ && li < wi);
                v2[tt][r] = s2 ? ls : ws_;
                c2[tt][r] = s2 ? li : wi;
                v1[tt][r] = gt ? ob1 : v1[tt][r];
                c1[tt][r] = gt ? oi1 : c1[tt][r];
            }
        }

    // each wave owns its 64 tokens exclusively -> direct store, no LDS merge
    if (n == 0) {
#pragma unroll
        for (int tt = 0; tt < 4; ++tt)
#pragma unroll
            for (int r = 0; r < 4; ++r) {
                const int token = t0 + w * 64 + tt * 16 + quad * 4 + r;
                const size_t o = (size_t)split * NT + token;
                sb1[o] = v1[tt][r]; si1[o] = c1[tt][r];
                sb2[o] = v2[tt][r]; si2[o] = c2[tt][r];
            }
    }
}

// ------------- combine: merge 8 splits, exact-rescore margin band -------------
__global__ __launch_bounds__(256) void lfq_combine(
    const float* __restrict__ sb1, const float* __restrict__ sb2,
    const int* __restrict__ si1, const int* __restrict__ si2,
    const float* __restrict__ xf, const float* __restrict__ cf,
    float* __restrict__ out, int out_size)
{
    const int t = blockIdx.x * 256 + threadIdx.x;

    float v[16]; int id[16];
#pragma unroll
    for (int s = 0; s < NSPLIT; ++s) {
        const size_t o = (size_t)s * NT + t;
        v[2*s]   = sb1[o]; id[2*s]   = si1[o];
        v[2*s+1] = sb2[o]; id[2*s+1] = si2[o];
    }
    float A1 = v[0]; int I1 = id[0];
#pragma unroll
    for (int k = 1; k < 16; ++k)
        if (v[k] > A1 || (v[k] == A1 && id[k] < I1)) { A1 = v[k]; I1 = id[k]; }

    int cnt = 0;
#pragma unroll
    for (int k = 0; k < 16; ++k) cnt += (v[k] >= A1 - MARGIN) ? 1 : 0;

    int bi = I1;
    if (cnt > 1) {
        float4 xr4[32];
        const float4* xrow = (const float4*)(xf + (size_t)t * ND);
#pragma unroll
        for (int i = 0; i < 32; ++i) xr4[i] = xrow[i];
        float bs = -__builtin_inff(); bool have = false; bi = 0;
#pragma unroll
        for (int k = 0; k < 16; ++k) {
            if (v[k] >= A1 - MARGIN) {
                float s = exact_dot(xr4, cf, id[k]);
                if (!have || s > bs || (s == bs && id[k] < bi)) { bs = s; bi = id[k]; have = true; }
            }
        }
    }
    out[t] = (float)bi;
    if (t == 0 && out_size > NT) out[NT] = 0.0f;
}

// ------------- fallback: round-3 exact fp32 kernel (tiny ws) -------------
__global__ __launch_bounds__(512) void lfq_fp32_argmax(
    const float* __restrict__ xf, const float* __restrict__ cf,
    float* __restrict__ out, int out_size)
{
    const int tid = threadIdx.x;
    const int w   = tid >> 6;
    const int tok = tid & 63;
    const int t0  = blockIdx.x * 64;
    __shared__ float s_sc[8][64];
    __shared__ int   s_ix[8][64];

    float4 xr[32];
    const float4* xrow = (const float4*)(xf + (size_t)(t0 + tok) * ND);
#pragma unroll
    for (int i = 0; i < 32; ++i) xr[i] = xrow[i];

    float bs = -__builtin_inff();
    int   bi = 0;
    const int c_begin = w * (NC / 8);
    for (int c = c_begin; c < c_begin + NC / 8; ++c) {
        float s = exact_dot(xr, cf, c);
        if (s > bs) { bs = s; bi = c; }
    }
    s_sc[w][tok] = bs; s_ix[w][tok] = bi;
    __syncthreads();
    if (tid < 64) {
        float bsf = s_sc[0][tid]; int bif = s_ix[0][tid];
#pragma unroll
        for (int ww = 1; ww < 8; ++ww) {
            float s2 = s_sc[ww][tid]; int ii = s_ix[ww][tid];
            if (s2 > bsf || (s2 == bsf && ii < bif)) { bsf = s2; bif = ii; }
        }
        out[t0 + tid] = (float)bif;
    }
    if (blockIdx.x == 0 && tid == 0 && out_size > NT) out[NT] = 0.0f;
}

extern "C" void kernel_launch(void* const* d_in, const int* in_sizes, int n_in,
                              void* d_out, int out_size, void* d_ws, size_t ws_size,
                              hipStream_t stream) {
    const float* x  = (const float*)d_in[0];
    const float* cb = (const float*)d_in[1];
    float* out = (float*)d_out;

    // ws: cbs 8.39MB (swizzled tile images) | sb1/sb2/si1/si2 512KB each
    const size_t NCE = (size_t)NC * ND;          // 2,097,152 codebook elements
    const size_t NEED = NCE * 2 * 2 + (size_t)NT * NSPLIT * 4 * 4;
    if (ws_size >= NEED) {
        char* ws = (char*)d_ws;
        unsigned short* cbs = (unsigned short*)ws;
        char* sp = ws + NCE * 4;
        float* sb1 = (float*)sp;
        float* sb2 = (float*)(sp + (size_t)NT * NSPLIT * 4);
        int*   si1 = (int*)  (sp + (size_t)NT * NSPLIT * 8);
        int*   si2 = (int*)  (sp + (size_t)NT * NSPLIT * 12);

        lfq_convert_cb<<<dim3(1024), dim3(512), 0, stream>>>(
            (const float4*)cb, cbs);
        lfq_stage1<<<dim3((NT / 256) * NSPLIT), dim3(256), 0, stream>>>(
            x, cbs, sb1, sb2, si1, si2);
        lfq_combine<<<dim3(64), dim3(256), 0, stream>>>(
            sb1, sb2, si1, si2, x, cb, out, out_size);
    } else {
        lfq_fp32_argmax<<<dim3(NT / 64), dim3(512), 0, stream>>>(x, cb, out, out_size);
    }
}

// Round 14
// 255.620 us; speedup vs baseline: 1.0587x; 1.0587x over previous
//
#include <hip/hip_runtime.h>
#include <hip/hip_bf16.h>

// LFQ argmax, round 14: r13 with the occupancy cap removed.
// r12/r13 forensics: OccupancyPercent identical (11.4/11.5%) despite halving
// LDS 64->32 KB -> residency blocker was NOT LDS. It was my own
// __launch_bounds__(256,1): w waves/EU for a B-thread block caps workgroups/CU
// at k = w*4/(B/64) = 1. (r11's (512,1) showed 22.6% only because an 8-wave
// block forces 2 waves/EU.) Fix: __launch_bounds__(256,2) -> k=2 blocks/CU,
// VGPR budget 256 >= 156 used, LDS 2x32KB <= 160KB. Two INDEPENDENT 4-wave
// blocks per CU: one block's per-tile barrier drain overlaps the other's MFMA
// (m114 co-scheduling). All else identical to r13.
// Numerics (validated r6-r13): 3-term split-bf16, 7-bit j-pack top-2
// (pk = 127 - (t*2+s)), per-split top-2, exact rescore of MARGIN band with
// band-count shortcut. Output float32[16385].
#define NT 16384
#define ND 128
#define NC 16384
#define NSPLIT 8
#define MARGIN 0.02f      // >20x the (split + 7-bit packing) comparison error
#define TILE_BYTES 16384  // 32 codes x 128 dims x 2B x (hi+lo)
#define NTILES 64         // tiles per 2048-code slice

typedef __bf16 bf16x8 __attribute__((ext_vector_type(8)));
typedef unsigned short u16x8 __attribute__((ext_vector_type(8)));
typedef float f32x4 __attribute__((ext_vector_type(4)));

static __device__ __forceinline__ unsigned short f2bf(float f) {
    unsigned u = __float_as_uint(f);
    return (unsigned short)((u + 0x7FFFu + ((u >> 16) & 1u)) >> 16);
}
static __device__ __forceinline__ float bf2f(unsigned short u) {
    return __uint_as_float(((unsigned)u) << 16);
}
static __device__ __forceinline__ bf16x8 u2b(u16x8 u) {
    return __builtin_bit_cast(bf16x8, u);
}
static __device__ __forceinline__ void gl2lds(const void* g, void* l) {
    __builtin_amdgcn_global_load_lds(
        (const __attribute__((address_space(1))) unsigned int*)g,
        (__attribute__((address_space(3))) unsigned int*)l, 16, 0, 0);
}

// ---- codebook fp32 -> bf16 hi/lo, 32-code tile images w/ chunk rotation ----
// Tile t: u16 span [t*8192, t*8192+8192): hi 4096 | lo 4096.
// Element (code c, dim d): r=c&31, pos=((d>>3)+r)&15 ->
//   hi at t*8192 + r*128 + pos*8 + (d&7); lo at +4096.
__global__ __launch_bounds__(512) void lfq_convert_cb(
    const float4* __restrict__ cb4, unsigned short* __restrict__ cbs)
{
    const unsigned i = blockIdx.x * 512 + threadIdx.x;   // 0..524287
    float4 v = cb4[i];
    const unsigned c    = i >> 5;
    const unsigned d0   = (i & 31u) << 2;
    const unsigned tile = c >> 5, r = c & 31u;
    const unsigned pos  = ((d0 >> 3) + r) & 15u;
    const unsigned base = tile * 8192u + r * 128u + pos * 8u + (d0 & 7u);
    ushort4 h, l;
    h.x = f2bf(v.x); l.x = f2bf(v.x - bf2f(h.x));
    h.y = f2bf(v.y); l.y = f2bf(v.y - bf2f(h.y));
    h.z = f2bf(v.z); l.z = f2bf(v.z - bf2f(h.z));
    h.w = f2bf(v.w); l.w = f2bf(v.w - bf2f(h.w));
    *(ushort4*)(cbs + base)        = h;
    *(ushort4*)(cbs + base + 4096) = l;
}

// round-3/4-validated exact fp32 dot (reads ORIGINAL fp32 codebook)
static __device__ __forceinline__ float exact_dot(
    const float4* __restrict__ xr4, const float* __restrict__ cf, int cidx)
{
    const float4* cr = (const float4*)(cf + (size_t)cidx * ND);
    float a0 = 0.f, a1 = 0.f, a2 = 0.f, a3 = 0.f;
#pragma unroll
    for (int i = 0; i < 32; i += 4) {
        float4 x0 = xr4[i+0], x1 = xr4[i+1], x2 = xr4[i+2], x3 = xr4[i+3];
        float4 c0 = cr[i+0],  c1 = cr[i+1],  c2 = cr[i+2],  c3 = cr[i+3];
        a0 += x0.x*c0.x + x0.y*c0.y + x0.z*c0.z + x0.w*c0.w;
        a1 += x1.x*c1.x + x1.y*c1.y + x1.z*c1.z + x1.w*c1.w;
        a2 += x2.x*c2.x + x2.y*c2.y + x2.z*c2.z + x2.w*c2.w;
        a3 += x3.x*c3.x + x3.y*c3.y + x3.z*c3.z + x3.w*c3.w;
    }
    return (a0 + a1) + (a2 + a3);
}

// ---- stage 1: grid 512 = 64 token-blocks(256 tok) x 8 splits (XCD-affine) ---
// Block: 256 threads = 4 waves; wave w covers tokens t0+w*64..+63 (tt=4),
// all waves sweep the 2048-code slice from LDS (32-code tiles).
__global__ __launch_bounds__(256, 2) void lfq_stage1(
    const float* __restrict__ xf, const unsigned short* __restrict__ cbs,
    float* __restrict__ sb1, float* __restrict__ sb2,
    int* __restrict__ si1, int* __restrict__ si2)
{
    const int split = blockIdx.x & 7;
    const int tb    = blockIdx.x >> 3;
    const int t0    = tb * 256;
    const int tid   = threadIdx.x;
    const int w     = tid >> 6;       // wave id = token-group, 0..3
    const int lane  = tid & 63;
    const int n     = lane & 15;
    const int quad  = lane >> 4;

    __shared__ __attribute__((aligned(16))) unsigned char lds[2 * TILE_BYTES];

    // A fragments: tokens t0 + w*64 + tt*16 + n, tt=0..3; fp32 -> bf16 hi/lo.
    bf16x8 ah[4][4], al[4][4];
#pragma unroll
    for (int tt = 0; tt < 4; ++tt) {
        const float* xr = xf + (size_t)(t0 + w * 64 + tt * 16 + n) * ND + quad * 8;
#pragma unroll
        for (int kk = 0; kk < 4; ++kk) {
            float4 v0 = *(const float4*)(xr + kk * 32);
            float4 v1 = *(const float4*)(xr + kk * 32 + 4);
            u16x8 hu, lu;
            hu[0] = f2bf(v0.x); lu[0] = f2bf(v0.x - bf2f(hu[0]));
            hu[1] = f2bf(v0.y); lu[1] = f2bf(v0.y - bf2f(hu[1]));
            hu[2] = f2bf(v0.z); lu[2] = f2bf(v0.z - bf2f(hu[2]));
            hu[3] = f2bf(v0.w); lu[3] = f2bf(v0.w - bf2f(hu[3]));
            hu[4] = f2bf(v1.x); lu[4] = f2bf(v1.x - bf2f(hu[4]));
            hu[5] = f2bf(v1.y); lu[5] = f2bf(v1.y - bf2f(hu[5]));
            hu[6] = f2bf(v1.z); lu[6] = f2bf(v1.z - bf2f(hu[6]));
            hu[7] = f2bf(v1.w); lu[7] = f2bf(v1.w - bf2f(hu[7]));
            ah[tt][kk] = u2b(hu);
            al[tt][kk] = u2b(lu);
        }
    }

    float b1[4][4], b2[4][4];
#pragma unroll
    for (int tt = 0; tt < 4; ++tt)
#pragma unroll
        for (int r = 0; r < 4; ++r) { b1[tt][r] = -3.0e38f; b2[tt][r] = -3.0e38f; }

    const unsigned char* gtiles =
        (const unsigned char*)cbs + (size_t)(split * NTILES) * TILE_BYTES;
    const unsigned sgo  = (unsigned)(tid * 16);   // global per-lane (contiguous)
    const unsigned ldso = (unsigned)(w * 1024);   // wave-uniform LDS segment

    // stage tile 0 into buffer 0 (4 rounds x 4 KB)
#pragma unroll
    for (int rd = 0; rd < 4; ++rd)
        gl2lds(gtiles + rd * 4096 + sgo, &lds[rd * 4096 + ldso]);
    __syncthreads();

    for (int t = 0; t < NTILES; ++t) {
        const unsigned bufo = (unsigned)(t & 1) * TILE_BYTES;
        if (t < NTILES - 1) {      // async prefetch of next tile (other buffer)
            const unsigned char* g = gtiles + (size_t)(t + 1) * TILE_BYTES;
            const unsigned nbo = (unsigned)((t + 1) & 1) * TILE_BYTES;
#pragma unroll
            for (int rd = 0; rd < 4; ++rd)
                gl2lds(g + rd * 4096 + sgo, &lds[nbo + rd * 4096 + ldso]);
        }
#pragma unroll
        for (int s = 0; s < 2; ++s) {
            const int r = s * 16 + n;                  // code row in tile, 0..31
            const unsigned rowh = bufo + (unsigned)r * 256;
            const unsigned rowl = rowh + 4096 * 2;     // lo half (+8192 B)
            const unsigned p0 = (unsigned)(quad + r) & 15u;
            const unsigned o0 = ((p0      ) & 15u) << 4;
            const unsigned o1 = ((p0 +  4u) & 15u) << 4;
            const unsigned o2 = ((p0 +  8u) & 15u) << 4;
            const unsigned o3 = ((p0 + 12u) & 15u) << 4;

            f32x4 a0 = {0.f,0.f,0.f,0.f}, a1 = {0.f,0.f,0.f,0.f};
            f32x4 a2 = {0.f,0.f,0.f,0.f}, a3 = {0.f,0.f,0.f,0.f};
            {   // hi B fragments: ah*Bh + al*Bh (32 MFMAs)
                bf16x8 q0 = *(const bf16x8*)&lds[rowh + o0];
                bf16x8 q1 = *(const bf16x8*)&lds[rowh + o1];
                bf16x8 q2 = *(const bf16x8*)&lds[rowh + o2];
                bf16x8 q3 = *(const bf16x8*)&lds[rowh + o3];
                a0 = __builtin_amdgcn_mfma_f32_16x16x32_bf16(ah[0][0], q0, a0, 0,0,0);
                a1 = __builtin_amdgcn_mfma_f32_16x16x32_bf16(ah[1][0], q0, a1, 0,0,0);
                a2 = __builtin_amdgcn_mfma_f32_16x16x32_bf16(ah[2][0], q0, a2, 0,0,0);
                a3 = __builtin_amdgcn_mfma_f32_16x16x32_bf16(ah[3][0], q0, a3, 0,0,0);
                a0 = __builtin_amdgcn_mfma_f32_16x16x32_bf16(ah[0][1], q1, a0, 0,0,0);
                a1 = __builtin_amdgcn_mfma_f32_16x16x32_bf16(ah[1][1], q1, a1, 0,0,0);
                a2 = __builtin_amdgcn_mfma_f32_16x16x32_bf16(ah[2][1], q1, a2, 0,0,0);
                a3 = __builtin_amdgcn_mfma_f32_16x16x32_bf16(ah[3][1], q1, a3, 0,0,0);
                a0 = __builtin_amdgcn_mfma_f32_16x16x32_bf16(ah[0][2], q2, a0, 0,0,0);
                a1 = __builtin_amdgcn_mfma_f32_16x16x32_bf16(ah[1][2], q2, a1, 0,0,0);
                a2 = __builtin_amdgcn_mfma_f32_16x16x32_bf16(ah[2][2], q2, a2, 0,0,0);
                a3 = __builtin_amdgcn_mfma_f32_16x16x32_bf16(ah[3][2], q2, a3, 0,0,0);
                a0 = __builtin_amdgcn_mfma_f32_16x16x32_bf16(ah[0][3], q3, a0, 0,0,0);
                a1 = __builtin_amdgcn_mfma_f32_16x16x32_bf16(ah[1][3], q3, a1, 0,0,0);
                a2 = __builtin_amdgcn_mfma_f32_16x16x32_bf16(ah[2][3], q3, a2, 0,0,0);
                a3 = __builtin_amdgcn_mfma_f32_16x16x32_bf16(ah[3][3], q3, a3, 0,0,0);
                a0 = __builtin_amdgcn_mfma_f32_16x16x32_bf16(al[0][0], q0, a0, 0,0,0);
                a1 = __builtin_amdgcn_mfma_f32_16x16x32_bf16(al[1][0], q0, a1, 0,0,0);
                a2 = __builtin_amdgcn_mfma_f32_16x16x32_bf16(al[2][0], q0, a2, 0,0,0);
                a3 = __builtin_amdgcn_mfma_f32_16x16x32_bf16(al[3][0], q0, a3, 0,0,0);
                a0 = __builtin_amdgcn_mfma_f32_16x16x32_bf16(al[0][1], q1, a0, 0,0,0);
                a1 = __builtin_amdgcn_mfma_f32_16x16x32_bf16(al[1][1], q1, a1, 0,0,0);
                a2 = __builtin_amdgcn_mfma_f32_16x16x32_bf16(al[2][1], q1, a2, 0,0,0);
                a3 = __builtin_amdgcn_mfma_f32_16x16x32_bf16(al[3][1], q1, a3, 0,0,0);
                a0 = __builtin_amdgcn_mfma_f32_16x16x32_bf16(al[0][2], q2, a0, 0,0,0);
                a1 = __builtin_amdgcn_mfma_f32_16x16x32_bf16(al[1][2], q2, a1, 0,0,0);
                a2 = __builtin_amdgcn_mfma_f32_16x16x32_bf16(al[2][2], q2, a2, 0,0,0);
                a3 = __builtin_amdgcn_mfma_f32_16x16x32_bf16(al[3][2], q2, a3, 0,0,0);
                a0 = __builtin_amdgcn_mfma_f32_16x16x32_bf16(al[0][3], q3, a0, 0,0,0);
                a1 = __builtin_amdgcn_mfma_f32_16x16x32_bf16(al[1][3], q3, a1, 0,0,0);
                a2 = __builtin_amdgcn_mfma_f32_16x16x32_bf16(al[2][3], q3, a2, 0,0,0);
                a3 = __builtin_amdgcn_mfma_f32_16x16x32_bf16(al[3][3], q3, a3, 0,0,0);
            }
            {   // lo B fragments: ah*Bl (16 MFMAs)
                bf16x8 q0 = *(const bf16x8*)&lds[rowl + o0];
                bf16x8 q1 = *(const bf16x8*)&lds[rowl + o1];
                bf16x8 q2 = *(const bf16x8*)&lds[rowl + o2];
                bf16x8 q3 = *(const bf16x8*)&lds[rowl + o3];
                a0 = __builtin_amdgcn_mfma_f32_16x16x32_bf16(ah[0][0], q0, a0, 0,0,0);
                a1 = __builtin_amdgcn_mfma_f32_16x16x32_bf16(ah[1][0], q0, a1, 0,0,0);
                a2 = __builtin_amdgcn_mfma_f32_16x16x32_bf16(ah[2][0], q0, a2, 0,0,0);
                a3 = __builtin_amdgcn_mfma_f32_16x16x32_bf16(ah[3][0], q0, a3, 0,0,0);
                a0 = __builtin_amdgcn_mfma_f32_16x16x32_bf16(ah[0][1], q1, a0, 0,0,0);
                a1 = __builtin_amdgcn_mfma_f32_16x16x32_bf16(ah[1][1], q1, a1, 0,0,0);
                a2 = __builtin_amdgcn_mfma_f32_16x16x32_bf16(ah[2][1], q1, a2, 0,0,0);
                a3 = __builtin_amdgcn_mfma_f32_16x16x32_bf16(ah[3][1], q1, a3, 0,0,0);
                a0 = __builtin_amdgcn_mfma_f32_16x16x32_bf16(ah[0][2], q2, a0, 0,0,0);
                a1 = __builtin_amdgcn_mfma_f32_16x16x32_bf16(ah[1][2], q2, a1, 0,0,0);
                a2 = __builtin_amdgcn_mfma_f32_16x16x32_bf16(ah[2][2], q2, a2, 0,0,0);
                a3 = __builtin_amdgcn_mfma_f32_16x16x32_bf16(ah[3][2], q2, a3, 0,0,0);
                a0 = __builtin_amdgcn_mfma_f32_16x16x32_bf16(ah[0][3], q3, a0, 0,0,0);
                a1 = __builtin_amdgcn_mfma_f32_16x16x32_bf16(ah[1][3], q3, a1, 0,0,0);
                a2 = __builtin_amdgcn_mfma_f32_16x16x32_bf16(ah[2][3], q3, a2, 0,0,0);
                a3 = __builtin_amdgcn_mfma_f32_16x16x32_bf16(ah[3][3], q3, a3, 0,0,0);
            }
            const unsigned pk = (unsigned)(127 - (t * 2 + s));
#pragma unroll
            for (int r4 = 0; r4 < 4; ++r4) {
                float p0v = __uint_as_float((__float_as_uint(a0[r4]) & 0xFFFFFF80u) | pk);
                b2[0][r4] = __builtin_amdgcn_fmed3f(p0v, b1[0][r4], b2[0][r4]);
                b1[0][r4] = fmaxf(p0v, b1[0][r4]);
                float p1v = __uint_as_float((__float_as_uint(a1[r4]) & 0xFFFFFF80u) | pk);
                b2[1][r4] = __builtin_amdgcn_fmed3f(p1v, b1[1][r4], b2[1][r4]);
                b1[1][r4] = fmaxf(p1v, b1[1][r4]);
                float p2v = __uint_as_float((__float_as_uint(a2[r4]) & 0xFFFFFF80u) | pk);
                b2[2][r4] = __builtin_amdgcn_fmed3f(p2v, b1[2][r4], b2[2][r4]);
                b1[2][r4] = fmaxf(p2v, b1[2][r4]);
                float p3v = __uint_as_float((__float_as_uint(a3[r4]) & 0xFFFFFF80u) | pk);
                b2[3][r4] = __builtin_amdgcn_fmed3f(p3v, b1[3][r4], b2[3][r4]);
                b1[3][r4] = fmaxf(p3v, b1[3][r4]);
            }
        }
        __syncthreads();   // drains prefetch (vmcnt) + protects buffer swap
    }

    // unpack (score, code) and cross-lane top-2 merge over 16 code-lanes
    const int cb_base = split * (NC / NSPLIT);
    float v1[4][4], v2[4][4];
    int   c1[4][4], c2[4][4];
#pragma unroll
    for (int tt = 0; tt < 4; ++tt)
#pragma unroll
        for (int r = 0; r < 4; ++r) {
            int j1 = 127 - (int)(__float_as_uint(b1[tt][r]) & 127u);
            int j2 = 127 - (int)(__float_as_uint(b2[tt][r]) & 127u);
            v1[tt][r] = b1[tt][r]; c1[tt][r] = cb_base + j1 * 16 + n;
            v2[tt][r] = b2[tt][r]; c2[tt][r] = cb_base + j2 * 16 + n;
        }

#pragma unroll
    for (int tt = 0; tt < 4; ++tt)
#pragma unroll
        for (int r = 0; r < 4; ++r) {
#pragma unroll
            for (int off = 1; off < 16; off <<= 1) {
                float ob1 = __shfl_xor(v1[tt][r], off, 64);
                int   oi1 = __shfl_xor(c1[tt][r], off, 64);
                float ob2 = __shfl_xor(v2[tt][r], off, 64);
                int   oi2 = __shfl_xor(c2[tt][r], off, 64);
                bool gt = (ob1 > v1[tt][r]) ||
                          (ob1 == v1[tt][r] && oi1 < c1[tt][r]);
                float ls = gt ? v1[tt][r] : ob1;
                int   li = gt ? c1[tt][r] : oi1;
                float ws_ = gt ? ob2 : v2[tt][r];
                int   wi = gt ? oi2 : c2[tt][r];
                bool s2 = (ls > ws_) || (ls == ws_ && li < wi);
                v2[tt][r] = s2 ? ls : ws_;
                c2[tt][r] = s2 ? li : wi;
                v1[tt][r] = gt ? ob1 : v1[tt][r];
                c1[tt][r] = gt ? oi1 : c1[tt][r];
            }
        }

    // each wave owns its 64 tokens exclusively -> direct store, no LDS merge
    if (n == 0) {
#pragma unroll
        for (int tt = 0; tt < 4; ++tt)
#pragma unroll
            for (int r = 0; r < 4; ++r) {
                const int token = t0 + w * 64 + tt * 16 + quad * 4 + r;
                const size_t o = (size_t)split * NT + token;
                sb1[o] = v1[tt][r]; si1[o] = c1[tt][r];
                sb2[o] = v2[tt][r]; si2[o] = c2[tt][r];
            }
    }
}

// ------------- combine: merge 8 splits, exact-rescore margin band -------------
__global__ __launch_bounds__(256) void lfq_combine(
    const float* __restrict__ sb1, const float* __restrict__ sb2,
    const int* __restrict__ si1, const int* __restrict__ si2,
    const float* __restrict__ xf, const float* __restrict__ cf,
    float* __restrict__ out, int out_size)
{
    const int t = blockIdx.x * 256 + threadIdx.x;

    float v[16]; int id[16];
#pragma unroll
    for (int s = 0; s < NSPLIT; ++s) {
        const size_t o = (size_t)s * NT + t;
        v[2*s]   = sb1[o]; id[2*s]   = si1[o];
        v[2*s+1] = sb2[o]; id[2*s+1] = si2[o];
    }
    float A1 = v[0]; int I1 = id[0];
#pragma unroll
    for (int k = 1; k < 16; ++k)
        if (v[k] > A1 || (v[k] == A1 && id[k] < I1)) { A1 = v[k]; I1 = id[k]; }

    int cnt = 0;
#pragma unroll
    for (int k = 0; k < 16; ++k) cnt += (v[k] >= A1 - MARGIN) ? 1 : 0;

    int bi = I1;
    if (cnt > 1) {
        float4 xr4[32];
        const float4* xrow = (const float4*)(xf + (size_t)t * ND);
#pragma unroll
        for (int i = 0; i < 32; ++i) xr4[i] = xrow[i];
        float bs = -__builtin_inff(); bool have = false; bi = 0;
#pragma unroll
        for (int k = 0; k < 16; ++k) {
            if (v[k] >= A1 - MARGIN) {
                float s = exact_dot(xr4, cf, id[k]);
                if (!have || s > bs || (s == bs && id[k] < bi)) { bs = s; bi = id[k]; have = true; }
            }
        }
    }
    out[t] = (float)bi;
    if (t == 0 && out_size > NT) out[NT] = 0.0f;
}

// ------------- fallback: round-3 exact fp32 kernel (tiny ws) -------------
__global__ __launch_bounds__(512) void lfq_fp32_argmax(
    const float* __restrict__ xf, const float* __restrict__ cf,
    float* __restrict__ out, int out_size)
{
    const int tid = threadIdx.x;
    const int w   = tid >> 6;
    const int tok = tid & 63;
    const int t0  = blockIdx.x * 64;
    __shared__ float s_sc[8][64];
    __shared__ int   s_ix[8][64];

    float4 xr[32];
    const float4* xrow = (const float4*)(xf + (size_t)(t0 + tok) * ND);
#pragma unroll
    for (int i = 0; i < 32; ++i) xr[i] = xrow[i];

    float bs = -__builtin_inff();
    int   bi = 0;
    const int c_begin = w * (NC / 8);
    for (int c = c_begin; c < c_begin + NC / 8; ++c) {
        float s = exact_dot(xr, cf, c);
        if (s > bs) { bs = s; bi = c; }
    }
    s_sc[w][tok] = bs; s_ix[w][tok] = bi;
    __syncthreads();
    if (tid < 64) {
        float bsf = s_sc[0][tid]; int bif = s_ix[0][tid];
#pragma unroll
        for (int ww = 1; ww < 8; ++ww) {
            float s2 = s_sc[ww][tid]; int ii = s_ix[ww][tid];
            if (s2 > bsf || (s2 == bsf && ii < bif)) { bsf = s2; bif = ii; }
        }
        out[t0 + tid] = (float)bif;
    }
    if (blockIdx.x == 0 && tid == 0 && out_size > NT) out[NT] = 0.0f;
}

extern "C" void kernel_launch(void* const* d_in, const int* in_sizes, int n_in,
                              void* d_out, int out_size, void* d_ws, size_t ws_size,
                              hipStream_t stream) {
    const float* x  = (const float*)d_in[0];
    const float* cb = (const float*)d_in[1];
    float* out = (float*)d_out;

    // ws: cbs 8.39MB (swizzled tile images) | sb1/sb2/si1/si2 512KB each
    const size_t NCE = (size_t)NC * ND;          // 2,097,152 codebook elements
    const size_t NEED = NCE * 2 * 2 + (size_t)NT * NSPLIT * 4 * 4;
    if (ws_size >= NEED) {
        char* ws = (char*)d_ws;
        unsigned short* cbs = (unsigned short*)ws;
        char* sp = ws + NCE * 4;
        float* sb1 = (float*)sp;
        float* sb2 = (float*)(sp + (size_t)NT * NSPLIT * 4);
        int*   si1 = (int*)  (sp + (size_t)NT * NSPLIT * 8);
        int*   si2 = (int*)  (sp + (size_t)NT * NSPLIT * 12);

        lfq_convert_cb<<<dim3(1024), dim3(512), 0, stream>>>(
            (const float4*)cb, cbs);
        lfq_stage1<<<dim3((NT / 256) * NSPLIT), dim3(256), 0, stream>>>(
            x, cbs, sb1, sb2, si1, si2);
        lfq_combine<<<dim3(64), dim3(256), 0, stream>>>(
            sb1, sb2, si1, si2, x, cb, out, out_size);
    } else {
        lfq_fp32_argmax<<<dim3(NT / 64), dim3(512), 0, stream>>>(x, cb, out, out_size);
    }
}